// Round 13
// baseline (244.085 us; speedup 1.0000x reference)
//
#include <hip/hip_runtime.h>
#include <math.h>

#define NDIM 16
#define NMLP 4
#define NL 4
#define NOUT 16
#define NS 512
#define NT 1024
#define LEPS 1e-5f
#define VPAD 516
#define KPAD 28

typedef __fp16 h2 __attribute__((ext_vector_type(2)));
typedef __fp16 h4 __attribute__((ext_vector_type(4)));
typedef __fp16 h8 __attribute__((ext_vector_type(8)));
typedef float f32x4 __attribute__((ext_vector_type(4)));

__device__ __forceinline__ h2 pk2(float x, float y) {
    return __builtin_amdgcn_cvt_pkrtz(x, y);
}

#define MFMA32(a,b,c) __builtin_amdgcn_mfma_f32_16x16x32_f16((a),(b),(c),0,0,0)

// 1024 threads/block, 1 block per batch element. grid == 256 == 1 block/CU.
// exp() is an LDS lookup: Q is pre-scaled by 0.5*log2(e)*128, the QK MFMA's
// C operand carries the +2048.5 index bias, so p = sExp[clamp(T,0,4095)]
// costs med3+cvt+addr+ds_read_u16 instead of a 16-cycle v_exp_f32.
// Phase B is split into two sequential q-tile passes (fits 64-VGPR budget,
// no scratch). Softmax denominators ride the MFMA pipe via an all-ones A-frag.
__global__ __launch_bounds__(NT, 4)
void vit_fused(const float* __restrict__ gx,
               const float* __restrict__ g_ln1g, const float* __restrict__ g_ln1b,
               const float* __restrict__ g_inw,  const float* __restrict__ g_inb,
               const float* __restrict__ g_outw, const float* __restrict__ g_outb,
               const float* __restrict__ g_ln2g, const float* __restrict__ g_ln2b,
               const float* __restrict__ g_w1,   const float* __restrict__ g_b1,
               const float* __restrict__ g_w2,   const float* __restrict__ g_b2,
               const float* __restrict__ g_hg,   const float* __restrict__ g_hb,
               const float* __restrict__ g_hw,   const float* __restrict__ g_hbias,
               float* __restrict__ gout)
{
    __shared__ __align__(16) __fp16 sKh[NS][KPAD];     // 28 KB K rows f16 (padded)
    __shared__ __align__(16) __fp16 sVT[NDIM][VPAD];   // ~16.1 KB V^T f16 (padded)
    __shared__ __align__(16) __fp16 sQO[NS][NDIM];     // 16 KB Q then O, f16
    __shared__ __align__(16) __fp16 sExp[4096];        // 8 KB exp2 LUT
    __shared__ __align__(16) float sWiw[NL*48*NDIM];   // 12 KB
    __shared__ float sWib[NL*48];
    __shared__ __align__(16) float sWow[NL*NDIM*NDIM]; // 4 KB
    __shared__ float sWob[NL*NDIM];
    __shared__ float sLn1g[NL*NDIM], sLn1b[NL*NDIM], sLn2g[NL*NDIM], sLn2b[NL*NDIM];
    __shared__ __align__(16) float sW1[NL*NMLP*NDIM];
    __shared__ float sB1[NL*NMLP];
    __shared__ __align__(16) float sW2[NL*NDIM*NMLP];
    __shared__ float sB2[NL*NDIM];
    __shared__ float sHg[NDIM], sHb[NDIM];
    __shared__ __align__(16) float sHw[NOUT*NDIM];
    __shared__ float sHbias[NOUT];

    const int tid = threadIdx.x;
    const int t   = tid & (NS-1);        // sequence row (phase A/C)
    const int hb  = (tid >> 9) << 3;     // 0 or 8: which 8 dims this thread computes
    const int b   = blockIdx.x;

    // wave geometry (phase B)
    const int w  = tid >> 6;             // 0..15
    const int l  = tid & 63;
    const int g  = l >> 4;               // 0..3 : lane group
    const int ql = l & 15;
    const int r0 = 32*w;                 // this wave's q-row base

    // ---- stage all weights to LDS once; fill exp LUT ----
    for (int i = tid; i < 4096; i += NT)
        sExp[i] = (__fp16)exp2f((i - 2048) * 0.0078125f);
    for (int i = tid; i < NL*48*NDIM; i += NT) sWiw[i] = g_inw[i];
    for (int i = tid; i < NL*48;       i += NT) sWib[i] = g_inb[i];
    for (int i = tid; i < NL*NDIM*NDIM; i += NT) sWow[i] = g_outw[i];
    if (tid < NL*NDIM) {
        sWob[tid]  = g_outb[tid];
        sLn1g[tid] = g_ln1g[tid];  sLn1b[tid] = g_ln1b[tid];
        sLn2g[tid] = g_ln2g[tid];  sLn2b[tid] = g_ln2b[tid];
        sB2[tid]   = g_b2[tid];
    }
    for (int i = tid; i < NL*NMLP*NDIM; i += NT) { sW1[i] = g_w1[i]; sW2[i] = g_w2[i]; }
    if (tid < NL*NMLP) sB1[tid] = g_b1[tid];
    if (tid < NDIM)  { sHg[tid] = g_hg[tid]; sHb[tid] = g_hb[tid]; }
    if (tid < NOUT)    sHbias[tid] = g_hbias[tid];
    for (int i = tid; i < NOUT*NDIM; i += NT) sHw[i] = g_hw[i];

    // ---- load my x row (both halves load the same row) ----
    float xr[NDIM];
    {
        const float4* xg4 = (const float4*)(gx + ((size_t)b*NS + t)*NDIM);
        float4 a = xg4[0], b4 = xg4[1], c4 = xg4[2], d4 = xg4[3];
        xr[0]=a.x;  xr[1]=a.y;  xr[2]=a.z;  xr[3]=a.w;
        xr[4]=b4.x; xr[5]=b4.y; xr[6]=b4.z; xr[7]=b4.w;
        xr[8]=c4.x; xr[9]=c4.y; xr[10]=c4.z; xr[11]=c4.w;
        xr[12]=d4.x; xr[13]=d4.y; xr[14]=d4.z; xr[15]=d4.w;
    }

    __syncthreads();   // weights + LUT staged

    for (int li = 0; li < NL; ++li) {
        // ================= Phase A: LN1 + qkv halves =================
        float mu = 0.f;
        #pragma unroll
        for (int c = 0; c < NDIM; ++c) mu += xr[c];
        mu *= (1.f/NDIM);
        float var = 0.f;
        #pragma unroll
        for (int c = 0; c < NDIM; ++c) { float d = xr[c]-mu; var += d*d; }
        var *= (1.f/NDIM);
        float rs = rsqrtf(var + LEPS);
        float hn[NDIM];
        #pragma unroll
        for (int c = 0; c < NDIM; ++c)
            hn[c] = (xr[c]-mu)*rs*sLn1g[li*NDIM+c] + sLn1b[li*NDIM+c];

        const float* iw = &sWiw[li*48*NDIM];
        const float* ib = &sWib[li*48];

        // my 8 q dims, scaled by 0.5*log2(e)*128 (LUT index scale); f16 to sQO
        {
            const float C = 92.332482616893658071f;   // 0.72134752... * 128
            float qf[8];
            #pragma unroll
            for (int r = 0; r < 8; ++r) {
                const float* wrow = &iw[(hb+r)*NDIM];
                float acc = ib[hb+r];
                #pragma unroll
                for (int c = 0; c < NDIM; ++c) acc += hn[c]*wrow[c];
                qf[r] = acc*C;
            }
            h4 qlo = __builtin_shufflevector(pk2(qf[0],qf[1]), pk2(qf[2],qf[3]), 0,1,2,3);
            h4 qhi = __builtin_shufflevector(pk2(qf[4],qf[5]), pk2(qf[6],qf[7]), 0,1,2,3);
            *(h4*)&sQO[t][hb]   = qlo;
            *(h4*)&sQO[t][hb+4] = qhi;
        }
        // my 8 k dims -> sKh (padded rows)
        {
            float kr[8];
            #pragma unroll
            for (int r = 0; r < 8; ++r) {
                const float* wrow = &iw[(16+hb+r)*NDIM];
                float acc = ib[16+hb+r];
                #pragma unroll
                for (int c = 0; c < NDIM; ++c) acc += hn[c]*wrow[c];
                kr[r] = acc;
            }
            h4 klo = __builtin_shufflevector(pk2(kr[0],kr[1]), pk2(kr[2],kr[3]), 0,1,2,3);
            h4 khi = __builtin_shufflevector(pk2(kr[4],kr[5]), pk2(kr[6],kr[7]), 0,1,2,3);
            *(h4*)&sKh[t][hb]   = klo;
            *(h4*)&sKh[t][hb+4] = khi;
        }
        // my 8 v dims -> sVT (transposed)
        {
            #pragma unroll
            for (int r = 0; r < 8; ++r) {
                const float* wrow = &iw[(32+hb+r)*NDIM];
                float acc = ib[32+hb+r];
                #pragma unroll
                for (int c = 0; c < NDIM; ++c) acc += hn[c]*wrow[c];
                sVT[hb+r][t] = (__fp16)acc;
            }
        }
        __syncthreads();   // B1: Q/K/V visible

        // ================= Phase B: MFMA attention, two q-tile passes =========
        #pragma unroll 1
        for (int qt = 0; qt < 2; ++qt) {
            h4 z4 = {};
            h8 z8 = {};
            h8 ones8 = {(__fp16)1.f,(__fp16)1.f,(__fp16)1.f,(__fp16)1.f,
                        (__fp16)1.f,(__fp16)1.f,(__fp16)1.f,(__fp16)1.f};
            h4 q4 = *(const h4*)&sQO[r0 + 16*qt + ql][4*g];
            h8 q8 = __builtin_shufflevector(q4, z4, 0,1,2,3,4,5,6,7);
            h8 bq[4];
            #pragma unroll
            for (int h = 0; h < 4; ++h) bq[h] = (g == h) ? q8 : z8;

            f32x4 zc = {0.f, 0.f, 0.f, 0.f};
            // +2048.5: LUT index bias (+0.5 makes truncation = round-to-nearest)
            f32x4 cbias = {2048.5f, 2048.5f, 2048.5f, 2048.5f};
            f32x4 acc[4];
            f32x4 sacc[4];
            #pragma unroll
            for (int h = 0; h < 4; ++h) { acc[h] = zc; sacc[h] = zc; }

            for (int jj = 0; jj < NS; jj += 32) {
                // K fragments for the two 16-key tiles (d padded 16->32)
                h4 ak0 = *(const h4*)&sKh[jj + ql][4*g];
                h4 ak1 = *(const h4*)&sKh[jj + 16 + ql][4*g];
                h8 a0 = __builtin_shufflevector(ak0, z4, 0,1,2,3,4,5,6,7);
                h8 a1 = __builtin_shufflevector(ak1, z4, 0,1,2,3,4,5,6,7);
                // V^T fragment covering both tiles (elems 0-3: tile0, 4-7: tile1)
                h4 av0 = *(const h4*)&sVT[ql][jj + 4*g];
                h4 av1 = *(const h4*)&sVT[ql][jj + 16 + 4*g];
                h8 av  = __builtin_shufflevector(av0, av1, 0,1,2,3,4,5,6,7);

                #pragma unroll
                for (int h = 0; h < 4; ++h) {
                    f32x4 T0 = MFMA32(a0, bq[h], cbias);
                    f32x4 T1 = MFMA32(a1, bq[h], cbias);
                    // exp via LUT: clamp -> trunc -> ds_read_u16
                    __fp16 e0, e1, e2, e3, e4, e5, e6, e7;
                    e0 = sExp[(int)fminf(fmaxf(T0[0], 0.f), 4095.f)];
                    e1 = sExp[(int)fminf(fmaxf(T0[1], 0.f), 4095.f)];
                    e2 = sExp[(int)fminf(fmaxf(T0[2], 0.f), 4095.f)];
                    e3 = sExp[(int)fminf(fmaxf(T0[3], 0.f), 4095.f)];
                    e4 = sExp[(int)fminf(fmaxf(T1[0], 0.f), 4095.f)];
                    e5 = sExp[(int)fminf(fmaxf(T1[1], 0.f), 4095.f)];
                    e6 = sExp[(int)fminf(fmaxf(T1[2], 0.f), 4095.f)];
                    e7 = sExp[(int)fminf(fmaxf(T1[3], 0.f), 4095.f)];
                    h8 pb = {e0, e1, e2, e3, e4, e5, e6, e7};
                    acc[h]  = MFMA32(av, pb, acc[h]);
                    sacc[h] = MFMA32(ones8, pb, sacc[h]);
                }
            }

            // extract head g's O^T rows, normalize, store to sQO.
            float sg = (g < 2) ? ((g == 0) ? sacc[0][0] : sacc[1][0])
                               : ((g == 2) ? sacc[2][0] : sacc[3][0]);
            f32x4 C = (g < 2) ? ((g == 0) ? acc[0] : acc[1])
                              : ((g == 2) ? acc[2] : acc[3]);
            float inv = 1.f / sg;
            h4 o4 = __builtin_shufflevector(pk2(C[0]*inv, C[1]*inv),
                                            pk2(C[2]*inv, C[3]*inv), 0,1,2,3);
            *(h4*)&sQO[r0 + 16*qt + ql][4*g] = o4;
        }
        __syncthreads();   // B2: O visible

        float of[NDIM];
        {
            float4 lo = *(const float4*)&sQO[t][0];
            float4 hi = *(const float4*)&sQO[t][8];
            const h2* l2  = (const h2*)&lo;
            const h2* h2p = (const h2*)&hi;
            #pragma unroll
            for (int i = 0; i < 4; ++i) {
                of[2*i]     = (float)l2[i].x;  of[2*i+1]   = (float)l2[i].y;
                of[8+2*i]   = (float)h2p[i].x; of[8+2*i+1] = (float)h2p[i].y;
            }
        }
        __syncthreads();   // B3: safe to overwrite LDS next layer

        // ================= Phase C: proj + residual, LN2 + MLP =================
        {
            const float* ow = &sWow[li*NDIM*NDIM];
            const float* ob = &sWob[li*NDIM];
            #pragma unroll
            for (int c = 0; c < NDIM; ++c) {
                float acc = ob[c];
                #pragma unroll
                for (int k = 0; k < NDIM; ++k) acc += of[k]*ow[c*NDIM+k];
                xr[c] += acc;
            }
        }
        {
            float mu2 = 0.f;
            #pragma unroll
            for (int c = 0; c < NDIM; ++c) mu2 += xr[c];
            mu2 *= (1.f/NDIM);
            float var2 = 0.f;
            #pragma unroll
            for (int c = 0; c < NDIM; ++c) { float d = xr[c]-mu2; var2 += d*d; }
            var2 *= (1.f/NDIM);
            float rs2 = rsqrtf(var2 + LEPS);
            float hn2[NDIM];
            #pragma unroll
            for (int c = 0; c < NDIM; ++c)
                hn2[c] = (xr[c]-mu2)*rs2*sLn2g[li*NDIM+c] + sLn2b[li*NDIM+c];

            const float* w1p = &sW1[li*NMLP*NDIM];
            float h1[NMLP];
            #pragma unroll
            for (int m = 0; m < NMLP; ++m) {
                float acc = sB1[li*NMLP+m];
                #pragma unroll
                for (int c = 0; c < NDIM; ++c) acc += hn2[c]*w1p[m*NDIM+c];
                h1[m] = 0.5f*acc*(1.f + erff(acc*0.70710678118654752f));
            }
            const float* w2p = &sW2[li*NDIM*NMLP];
            #pragma unroll
            for (int c = 0; c < NDIM; ++c) {
                float acc = sB2[li*NDIM+c];
                #pragma unroll
                for (int m = 0; m < NMLP; ++m) acc += h1[m]*w2p[c*NMLP+m];
                xr[c] += acc;
            }
        }
    }

    // ---- head: only row 0 ----
    if (tid == 0) {
        float mu = 0.f;
        #pragma unroll
        for (int c = 0; c < NDIM; ++c) mu += xr[c];
        mu *= (1.f/NDIM);
        float var = 0.f;
        #pragma unroll
        for (int c = 0; c < NDIM; ++c) { float d = xr[c]-mu; var += d*d; }
        var *= (1.f/NDIM);
        float rs = rsqrtf(var + LEPS);
        float hn[NDIM];
        #pragma unroll
        for (int c = 0; c < NDIM; ++c)
            hn[c] = (xr[c]-mu)*rs*sHg[c] + sHb[c];
        #pragma unroll
        for (int oi = 0; oi < NOUT; ++oi) {
            float acc = sHbias[oi];
            #pragma unroll
            for (int c = 0; c < NDIM; ++c) acc += hn[c]*sHw[oi*NDIM+c];
            gout[b*NOUT + oi] = acc;
        }
    }
}

extern "C" void kernel_launch(void* const* d_in, const int* in_sizes, int n_in,
                              void* d_out, int out_size, void* d_ws, size_t ws_size,
                              hipStream_t stream) {
    const float* x       = (const float*)d_in[0];
    const float* ln1_g   = (const float*)d_in[1];
    const float* ln1_b   = (const float*)d_in[2];
    const float* in_w    = (const float*)d_in[3];
    const float* in_b    = (const float*)d_in[4];
    const float* out_w   = (const float*)d_in[5];
    const float* out_b   = (const float*)d_in[6];
    const float* ln2_g   = (const float*)d_in[7];
    const float* ln2_b   = (const float*)d_in[8];
    const float* w1      = (const float*)d_in[9];
    const float* b1      = (const float*)d_in[10];
    const float* w2      = (const float*)d_in[11];
    const float* b2      = (const float*)d_in[12];
    const float* head_g  = (const float*)d_in[13];
    const float* head_b  = (const float*)d_in[14];
    const float* head_w  = (const float*)d_in[15];
    const float* head_bias = (const float*)d_in[16];
    float* out = (float*)d_out;

    const int B = in_sizes[0] / (NS * NDIM);   // 256

    vit_fused<<<B, NT, 0, stream>>>(x, ln1_g, ln1_b, in_w, in_b, out_w, out_b,
                                    ln2_g, ln2_b, w1, b1, w2, b2,
                                    head_g, head_b, head_w, head_bias, out);
}

// Round 14
// 169.762 us; speedup vs baseline: 1.4378x; 1.4378x over previous
//
#include <hip/hip_runtime.h>
#include <math.h>

#define NDIM 16
#define NMLP 4
#define NL 4
#define NOUT 16
#define NS 512
#define NT 1024
#define LEPS 1e-5f
#define VPAD 516
#define KPAD 28

typedef __fp16 h2 __attribute__((ext_vector_type(2)));
typedef __fp16 h4 __attribute__((ext_vector_type(4)));
typedef __fp16 h8 __attribute__((ext_vector_type(8)));
typedef float f32x4 __attribute__((ext_vector_type(4)));

__device__ __forceinline__ h2 pk2(float x, float y) {
    return __builtin_amdgcn_cvt_pkrtz(x, y);
}

__device__ __forceinline__ float fexp2(float x) {
#if __has_builtin(__builtin_amdgcn_exp2f)
    return __builtin_amdgcn_exp2f(x);
#else
    return exp2f(x);
#endif
}

#define MFMA32(a,b,c) __builtin_amdgcn_mfma_f32_16x16x32_f16((a),(b),(c),0,0,0)

// 1024 threads/block, 1 block per batch element. grid == 256 == 1 block/CU.
// Phase B is split into TWO sequential q-tile passes so the per-pass live
// register set fits the compiler's 64-VGPR budget without scratch spills.
// Phase A (per-thread): LN1 + qkv halves -> Q,K (row-major f16, padded), V^T in LDS.
// Phase B (per-wave MFMA, 16x16x32f16): wave w owns q-rows 32w..32w+31.
//   QK: A = K-tile (d padded 16->32 with zeros), B = per-head-masked Q.
//   scores -> v_exp_f32 -> pk2 -> PV B-frag; PV contracts 32 keys per MFMA.
//   Softmax denominators on the MFMA pipe via an all-ones A-frag.
// Phase C (per-thread): o-proj + residual + LN2 + MLP + residual.
// NOTE (measured): exp() substitutes all regress — LDS LUT gathers hit 35M
// bank conflicts (+43%), packed-f16 poly eats more issue slots than the
// quarter-rate v_exp_f32 (+57%). v_exp_f32 stays.
__global__ __launch_bounds__(NT, 4)
void vit_fused(const float* __restrict__ gx,
               const float* __restrict__ g_ln1g, const float* __restrict__ g_ln1b,
               const float* __restrict__ g_inw,  const float* __restrict__ g_inb,
               const float* __restrict__ g_outw, const float* __restrict__ g_outb,
               const float* __restrict__ g_ln2g, const float* __restrict__ g_ln2b,
               const float* __restrict__ g_w1,   const float* __restrict__ g_b1,
               const float* __restrict__ g_w2,   const float* __restrict__ g_b2,
               const float* __restrict__ g_hg,   const float* __restrict__ g_hb,
               const float* __restrict__ g_hw,   const float* __restrict__ g_hbias,
               float* __restrict__ gout)
{
    __shared__ __align__(16) __fp16 sKh[NS][KPAD];     // 28 KB K rows f16 (padded)
    __shared__ __align__(16) __fp16 sVT[NDIM][VPAD];   // ~16.1 KB V^T f16 (padded)
    __shared__ __align__(16) __fp16 sQO[NS][NDIM];     // 16 KB Q then O, f16
    __shared__ __align__(16) float sWiw[NL*48*NDIM];   // 12 KB
    __shared__ float sWib[NL*48];
    __shared__ __align__(16) float sWow[NL*NDIM*NDIM]; // 4 KB
    __shared__ float sWob[NL*NDIM];
    __shared__ float sLn1g[NL*NDIM], sLn1b[NL*NDIM], sLn2g[NL*NDIM], sLn2b[NL*NDIM];
    __shared__ __align__(16) float sW1[NL*NMLP*NDIM];
    __shared__ float sB1[NL*NMLP];
    __shared__ __align__(16) float sW2[NL*NDIM*NMLP];
    __shared__ float sB2[NL*NDIM];
    __shared__ float sHg[NDIM], sHb[NDIM];
    __shared__ __align__(16) float sHw[NOUT*NDIM];
    __shared__ float sHbias[NOUT];

    const int tid = threadIdx.x;
    const int t   = tid & (NS-1);        // sequence row (phase A/C)
    const int hb  = (tid >> 9) << 3;     // 0 or 8: which 8 dims this thread computes
    const int b   = blockIdx.x;

    // wave geometry (phase B)
    const int w  = tid >> 6;             // 0..15
    const int l  = tid & 63;
    const int g  = l >> 4;               // 0..3 : lane group
    const int ql = l & 15;
    const int r0 = 32*w;                 // this wave's q-row base

    // ---- stage all weights to LDS once ----
    for (int i = tid; i < NL*48*NDIM; i += NT) sWiw[i] = g_inw[i];
    for (int i = tid; i < NL*48;       i += NT) sWib[i] = g_inb[i];
    for (int i = tid; i < NL*NDIM*NDIM; i += NT) sWow[i] = g_outw[i];
    if (tid < NL*NDIM) {
        sWob[tid]  = g_outb[tid];
        sLn1g[tid] = g_ln1g[tid];  sLn1b[tid] = g_ln1b[tid];
        sLn2g[tid] = g_ln2g[tid];  sLn2b[tid] = g_ln2b[tid];
        sB2[tid]   = g_b2[tid];
    }
    for (int i = tid; i < NL*NMLP*NDIM; i += NT) { sW1[i] = g_w1[i]; sW2[i] = g_w2[i]; }
    if (tid < NL*NMLP) sB1[tid] = g_b1[tid];
    if (tid < NDIM)  { sHg[tid] = g_hg[tid]; sHb[tid] = g_hb[tid]; }
    if (tid < NOUT)    sHbias[tid] = g_hbias[tid];
    for (int i = tid; i < NOUT*NDIM; i += NT) sHw[i] = g_hw[i];

    // ---- load my x row (both halves load the same row) ----
    float xr[NDIM];
    {
        const float4* xg4 = (const float4*)(gx + ((size_t)b*NS + t)*NDIM);
        float4 a = xg4[0], b4 = xg4[1], c4 = xg4[2], d4 = xg4[3];
        xr[0]=a.x;  xr[1]=a.y;  xr[2]=a.z;  xr[3]=a.w;
        xr[4]=b4.x; xr[5]=b4.y; xr[6]=b4.z; xr[7]=b4.w;
        xr[8]=c4.x; xr[9]=c4.y; xr[10]=c4.z; xr[11]=c4.w;
        xr[12]=d4.x; xr[13]=d4.y; xr[14]=d4.z; xr[15]=d4.w;
    }

    __syncthreads();   // weights staged

    for (int li = 0; li < NL; ++li) {
        // ================= Phase A: LN1 + qkv halves =================
        float mu = 0.f;
        #pragma unroll
        for (int c = 0; c < NDIM; ++c) mu += xr[c];
        mu *= (1.f/NDIM);
        float var = 0.f;
        #pragma unroll
        for (int c = 0; c < NDIM; ++c) { float d = xr[c]-mu; var += d*d; }
        var *= (1.f/NDIM);
        float rs = rsqrtf(var + LEPS);
        float hn[NDIM];
        #pragma unroll
        for (int c = 0; c < NDIM; ++c)
            hn[c] = (xr[c]-mu)*rs*sLn1g[li*NDIM+c] + sLn1b[li*NDIM+c];

        const float* iw = &sWiw[li*48*NDIM];
        const float* ib = &sWib[li*48];

        // my 8 q dims, scaled by 0.5*log2(e); write f16 to sQO
        {
            const float C = 0.72134752044448170368f;
            float qf[8];
            #pragma unroll
            for (int r = 0; r < 8; ++r) {
                const float* wrow = &iw[(hb+r)*NDIM];
                float acc = ib[hb+r];
                #pragma unroll
                for (int c = 0; c < NDIM; ++c) acc += hn[c]*wrow[c];
                qf[r] = acc*C;
            }
            h4 qlo = __builtin_shufflevector(pk2(qf[0],qf[1]), pk2(qf[2],qf[3]), 0,1,2,3);
            h4 qhi = __builtin_shufflevector(pk2(qf[4],qf[5]), pk2(qf[6],qf[7]), 0,1,2,3);
            *(h4*)&sQO[t][hb]   = qlo;
            *(h4*)&sQO[t][hb+4] = qhi;
        }
        // my 8 k dims -> sKh (padded rows)
        {
            float kr[8];
            #pragma unroll
            for (int r = 0; r < 8; ++r) {
                const float* wrow = &iw[(16+hb+r)*NDIM];
                float acc = ib[16+hb+r];
                #pragma unroll
                for (int c = 0; c < NDIM; ++c) acc += hn[c]*wrow[c];
                kr[r] = acc;
            }
            h4 klo = __builtin_shufflevector(pk2(kr[0],kr[1]), pk2(kr[2],kr[3]), 0,1,2,3);
            h4 khi = __builtin_shufflevector(pk2(kr[4],kr[5]), pk2(kr[6],kr[7]), 0,1,2,3);
            *(h4*)&sKh[t][hb]   = klo;
            *(h4*)&sKh[t][hb+4] = khi;
        }
        // my 8 v dims -> sVT (transposed)
        {
            #pragma unroll
            for (int r = 0; r < 8; ++r) {
                const float* wrow = &iw[(32+hb+r)*NDIM];
                float acc = ib[32+hb+r];
                #pragma unroll
                for (int c = 0; c < NDIM; ++c) acc += hn[c]*wrow[c];
                sVT[hb+r][t] = (__fp16)acc;
            }
        }
        __syncthreads();   // B1: Q/K/V visible

        // ================= Phase B: MFMA attention, two q-tile passes =========
        #pragma unroll 1
        for (int qt = 0; qt < 2; ++qt) {
            h4 z4 = {};
            h8 z8 = {};
            h8 ones8 = {(__fp16)1.f,(__fp16)1.f,(__fp16)1.f,(__fp16)1.f,
                        (__fp16)1.f,(__fp16)1.f,(__fp16)1.f,(__fp16)1.f};
            h4 q4 = *(const h4*)&sQO[r0 + 16*qt + ql][4*g];
            h8 q8 = __builtin_shufflevector(q4, z4, 0,1,2,3,4,5,6,7);
            h8 bq[4];
            #pragma unroll
            for (int h = 0; h < 4; ++h) bq[h] = (g == h) ? q8 : z8;

            f32x4 zc = {0.f, 0.f, 0.f, 0.f};
            f32x4 acc[4];
            f32x4 sacc[4];
            #pragma unroll
            for (int h = 0; h < 4; ++h) { acc[h] = zc; sacc[h] = zc; }

            for (int jj = 0; jj < NS; jj += 32) {
                // K fragments for the two 16-key tiles (d padded 16->32)
                h4 ak0 = *(const h4*)&sKh[jj + ql][4*g];
                h4 ak1 = *(const h4*)&sKh[jj + 16 + ql][4*g];
                h8 a0 = __builtin_shufflevector(ak0, z4, 0,1,2,3,4,5,6,7);
                h8 a1 = __builtin_shufflevector(ak1, z4, 0,1,2,3,4,5,6,7);
                // V^T fragment covering both tiles (elems 0-3: tile0, 4-7: tile1)
                h4 av0 = *(const h4*)&sVT[ql][jj + 4*g];
                h4 av1 = *(const h4*)&sVT[ql][jj + 16 + 4*g];
                h8 av  = __builtin_shufflevector(av0, av1, 0,1,2,3,4,5,6,7);

                #pragma unroll
                for (int h = 0; h < 4; ++h) {
                    f32x4 T0 = MFMA32(a0, bq[h], zc);
                    f32x4 T1 = MFMA32(a1, bq[h], zc);
                    h2 r0h = pk2(fexp2(T0[0]), fexp2(T0[1]));
                    h2 r1h = pk2(fexp2(T0[2]), fexp2(T0[3]));
                    h2 r2h = pk2(fexp2(T1[0]), fexp2(T1[1]));
                    h2 r3h = pk2(fexp2(T1[2]), fexp2(T1[3]));
                    h8 pb = __builtin_shufflevector(
                                __builtin_shufflevector(r0h, r1h, 0,1,2,3),
                                __builtin_shufflevector(r2h, r3h, 0,1,2,3),
                                0,1,2,3,4,5,6,7);
                    acc[h]  = MFMA32(av, pb, acc[h]);
                    sacc[h] = MFMA32(ones8, pb, sacc[h]);
                }
            }

            // extract head g's O^T rows, normalize, store to sQO.
            // sacc C-frag: every element of sacc[h] = sum_k p_h[k][qr].
            float sg = (g < 2) ? ((g == 0) ? sacc[0][0] : sacc[1][0])
                               : ((g == 2) ? sacc[2][0] : sacc[3][0]);
            f32x4 C = (g < 2) ? ((g == 0) ? acc[0] : acc[1])
                              : ((g == 2) ? acc[2] : acc[3]);
            float inv = 1.f / sg;
            h4 o4 = __builtin_shufflevector(pk2(C[0]*inv, C[1]*inv),
                                            pk2(C[2]*inv, C[3]*inv), 0,1,2,3);
            *(h4*)&sQO[r0 + 16*qt + ql][4*g] = o4;
        }
        __syncthreads();   // B2: O visible

        float of[NDIM];
        {
            float4 lo = *(const float4*)&sQO[t][0];
            float4 hi = *(const float4*)&sQO[t][8];
            const h2* l2  = (const h2*)&lo;
            const h2* h2p = (const h2*)&hi;
            #pragma unroll
            for (int i = 0; i < 4; ++i) {
                of[2*i]     = (float)l2[i].x;  of[2*i+1]   = (float)l2[i].y;
                of[8+2*i]   = (float)h2p[i].x; of[8+2*i+1] = (float)h2p[i].y;
            }
        }
        __syncthreads();   // B3: safe to overwrite LDS next layer

        // ================= Phase C: proj + residual, LN2 + MLP =================
        {
            const float* ow = &sWow[li*NDIM*NDIM];
            const float* ob = &sWob[li*NDIM];
            #pragma unroll
            for (int c = 0; c < NDIM; ++c) {
                float acc = ob[c];
                #pragma unroll
                for (int k = 0; k < NDIM; ++k) acc += of[k]*ow[c*NDIM+k];
                xr[c] += acc;
            }
        }
        {
            float mu2 = 0.f;
            #pragma unroll
            for (int c = 0; c < NDIM; ++c) mu2 += xr[c];
            mu2 *= (1.f/NDIM);
            float var2 = 0.f;
            #pragma unroll
            for (int c = 0; c < NDIM; ++c) { float d = xr[c]-mu2; var2 += d*d; }
            var2 *= (1.f/NDIM);
            float rs2 = rsqrtf(var2 + LEPS);
            float hn2[NDIM];
            #pragma unroll
            for (int c = 0; c < NDIM; ++c)
                hn2[c] = (xr[c]-mu2)*rs2*sLn2g[li*NDIM+c] + sLn2b[li*NDIM+c];

            const float* w1p = &sW1[li*NMLP*NDIM];
            float h1[NMLP];
            #pragma unroll
            for (int m = 0; m < NMLP; ++m) {
                float acc = sB1[li*NMLP+m];
                #pragma unroll
                for (int c = 0; c < NDIM; ++c) acc += hn2[c]*w1p[m*NDIM+c];
                h1[m] = 0.5f*acc*(1.f + erff(acc*0.70710678118654752f));
            }
            const float* w2p = &sW2[li*NDIM*NMLP];
            #pragma unroll
            for (int c = 0; c < NDIM; ++c) {
                float acc = sB2[li*NDIM+c];
                #pragma unroll
                for (int m = 0; m < NMLP; ++m) acc += h1[m]*w2p[c*NMLP+m];
                xr[c] += acc;
            }
        }
    }

    // ---- head: only row 0 ----
    if (tid == 0) {
        float mu = 0.f;
        #pragma unroll
        for (int c = 0; c < NDIM; ++c) mu += xr[c];
        mu *= (1.f/NDIM);
        float var = 0.f;
        #pragma unroll
        for (int c = 0; c < NDIM; ++c) { float d = xr[c]-mu; var += d*d; }
        var *= (1.f/NDIM);
        float rs = rsqrtf(var + LEPS);
        float hn[NDIM];
        #pragma unroll
        for (int c = 0; c < NDIM; ++c)
            hn[c] = (xr[c]-mu)*rs*sHg[c] + sHb[c];
        #pragma unroll
        for (int oi = 0; oi < NOUT; ++oi) {
            float acc = sHbias[oi];
            #pragma unroll
            for (int c = 0; c < NDIM; ++c) acc += hn[c]*sHw[oi*NDIM+c];
            gout[b*NOUT + oi] = acc;
        }
    }
}

extern "C" void kernel_launch(void* const* d_in, const int* in_sizes, int n_in,
                              void* d_out, int out_size, void* d_ws, size_t ws_size,
                              hipStream_t stream) {
    const float* x       = (const float*)d_in[0];
    const float* ln1_g   = (const float*)d_in[1];
    const float* ln1_b   = (const float*)d_in[2];
    const float* in_w    = (const float*)d_in[3];
    const float* in_b    = (const float*)d_in[4];
    const float* out_w   = (const float*)d_in[5];
    const float* out_b   = (const float*)d_in[6];
    const float* ln2_g   = (const float*)d_in[7];
    const float* ln2_b   = (const float*)d_in[8];
    const float* w1      = (const float*)d_in[9];
    const float* b1      = (const float*)d_in[10];
    const float* w2      = (const float*)d_in[11];
    const float* b2      = (const float*)d_in[12];
    const float* head_g  = (const float*)d_in[13];
    const float* head_b  = (const float*)d_in[14];
    const float* head_w  = (const float*)d_in[15];
    const float* head_bias = (const float*)d_in[16];
    float* out = (float*)d_out;

    const int B = in_sizes[0] / (NS * NDIM);   // 256

    vit_fused<<<B, NT, 0, stream>>>(x, ln1_g, ln1_b, in_w, in_b, out_w, out_b,
                                    ln2_g, ln2_b, w1, b1, w2, b2,
                                    head_g, head_b, head_w, head_bias, out);
}